// Round 17
// baseline (56.421 us; speedup 1.0000x reference)
//
#include <hip/hip_runtime.h>

typedef __attribute__((ext_vector_type(8))) short bf16x8;
typedef __attribute__((ext_vector_type(8))) unsigned short ushort8;
typedef __attribute__((ext_vector_type(4))) float f32x4;
typedef __attribute__((ext_vector_type(4))) unsigned uint4v;

static __device__ __forceinline__ unsigned short f2bf(float f) {
  union { float f; unsigned u; } v; v.f = f;
  unsigned r = v.u + 0x7FFFu + ((v.u >> 16) & 1u);
  return (unsigned short)(r >> 16);
}
static __device__ __forceinline__ int iclamp(int x, int lo, int hi) {
  return x < lo ? lo : (x > hi ? hi : x);
}
// async global->LDS, 16B per lane; LDS dest = wave-uniform base + lane*16
static __device__ __forceinline__ void gl_lds16(const void* g, void* l) {
  __builtin_amdgcn_global_load_lds(
      (const __attribute__((address_space(1))) void*)g,
      (__attribute__((address_space(3))) void*)l, 16, 0, 0);
}

// ---------------- weights fp32 -> bf16 (2.6 MB fp32; x converts in-GEMM) ----------------
__global__ void cvt_w(const float* __restrict__ w_in,
                      const float* __restrict__ w_out,
                      unsigned short* __restrict__ wbin,
                      unsigned short* __restrict__ wbo) {
  const int NWI4 = 196608, NWO4 = 65536;  // float4 counts
  const int total = NWI4 + NWO4;          // 262144 = 256*256*4
  for (int i = blockIdx.x * blockDim.x + threadIdx.x; i < total;
       i += gridDim.x * blockDim.x) {
    const float* src = (i < NWI4) ? w_in : w_out;
    unsigned short* dst = (i < NWI4) ? wbin : wbo;
    const int o = (i < NWI4) ? i : i - NWI4;
    float4 v = reinterpret_cast<const float4*>(src)[o];
    ushort4 u;
    u.x = f2bf(v.x); u.y = f2bf(v.y); u.z = f2bf(v.z); u.w = f2bf(v.w);
    reinterpret_cast<ushort4*>(dst)[o] = u;
  }
}

// ------- GEMM1: C[M][N](bf16) = A[M][K](FP32, converted on read) * B[N][K](bf16)^T + bias -------
// r14 schedule exactly (2-phase dbuf, gl_lds w16, post-MFMA vmcnt(0)+barrier),
// but A staged as fp32 (eliminates the cvt-x kernel's 48 MB round-trip):
//   As[2][128][32] fp32 (32 KB) + Bs[2][128][32] bf16 (16 KB) = 48 KB.
//   A stage: 8 rows/instr (row=lane>>3), src chunk (lane&7)^(lane>>3) -> T21
//   LDS[row][c] = G[row][c^(row&7)] (chunk = 16B = 4 fp32; row = 8 chunks).
//   A read: fp32 chunks {2k, 2k+1} at XORed addrs -> 2x b128 -> 4x
//   v_cvt_pk_bf16_f32 (RNE, == f2bf) -> bf16x8 fragment.
__global__ __launch_bounds__(256) void gemm_xf32_bt(
    const float* __restrict__ A, const unsigned short* __restrict__ B,
    const float* __restrict__ bias, unsigned short* __restrict__ C,
    int M, int N, int K) {
  __shared__ float As[2][128][32];           // 32 KB
  __shared__ unsigned short Bs[2][128][32];  // 16 KB
  const int tid = threadIdx.x;
  const int lane = tid & 63;
  const int wid = tid >> 6;

  // XCD-aware bijective swizzle (nwg = 768)
  const int nwg = gridDim.x * gridDim.y;
  const int orig = blockIdx.y * gridDim.x + blockIdx.x;
  const int q = nwg >> 3, r = nwg & 7;
  const int xcd = orig & 7, lid = orig >> 3;
  const int swz = (xcd < r ? xcd * (q + 1) : r * (q + 1) + (xcd - r) * q) + lid;
  const int bm = (swz / gridDim.x) * 128;
  const int bn = (swz % gridDim.x) * 128;

  const int wr = (wid >> 1) * 64;
  const int wc = (wid & 1) * 64;
  const int row16 = lane & 15;
  const int kgrp = lane >> 4;
  const int rswB = row16 & 3;  // B read swizzle key (4-chunk bf16 rows)
  const int rswA = row16 & 7;  // A read swizzle key (8-chunk fp32 rows)

  // A staging: one gl_lds16 = 8 rows x 128B; row lane>>3, chunk lane&7
  const float* gA = A + (size_t)(bm + wid * 32 + (lane >> 3)) * K +
                    ((lane & 7) ^ (lane >> 3)) * 4;
  // B staging: one gl_lds16 = 16 rows x 64B; row lane>>2, chunk lane&3
  const unsigned short* gB = B + (size_t)(bn + wid * 32 + (lane >> 2)) * K +
                             ((lane & 3) ^ ((lane >> 2) & 3)) * 8;
  const size_t K8 = (size_t)8 * K;
  const size_t K16 = (size_t)16 * K;

#define STAGE(buf, k0)                                                      \
  {                                                                         \
    _Pragma("unroll") for (int j = 0; j < 4; ++j)                           \
        gl_lds16(gA + j * K8 + (k0), &As[buf][wid * 32 + j * 8][0]);        \
    _Pragma("unroll") for (int j = 0; j < 2; ++j)                           \
        gl_lds16(gB + j * K16 + (k0), &Bs[buf][wid * 32 + j * 16][0]);      \
  }

  f32x4 acc[4][4] = {};

  STAGE(0, 0);
  asm volatile("s_waitcnt vmcnt(0)" ::: "memory");
  __builtin_amdgcn_s_barrier();

  const int NT = K >> 5;  // 16
  for (int t = 0; t < NT; ++t) {
    const int cur = t & 1;
    if (t + 1 < NT) STAGE(cur ^ 1, (t + 1) * 32);
    bf16x8 af[4], bfr[4];
#pragma unroll
    for (int ni = 0; ni < 4; ++ni)
      bfr[ni] = *reinterpret_cast<const bf16x8*>(
          &Bs[cur][wc + ni * 16 + row16][(kgrp ^ rswB) * 8]);
#pragma unroll
    for (int mi = 0; mi < 4; ++mi) {
      const int rr = wr + mi * 16 + row16;
      f32x4 a0 = *reinterpret_cast<const f32x4*>(
          &As[cur][rr][((kgrp * 2) ^ rswA) * 4]);
      f32x4 a1 = *reinterpret_cast<const f32x4*>(
          &As[cur][rr][((kgrp * 2 + 1) ^ rswA) * 4]);
      unsigned p0, p1, p2, p3;
      asm("v_cvt_pk_bf16_f32 %0, %1, %2" : "=v"(p0) : "v"(a0[0]), "v"(a0[1]));
      asm("v_cvt_pk_bf16_f32 %0, %1, %2" : "=v"(p1) : "v"(a0[2]), "v"(a0[3]));
      asm("v_cvt_pk_bf16_f32 %0, %1, %2" : "=v"(p2) : "v"(a1[0]), "v"(a1[1]));
      asm("v_cvt_pk_bf16_f32 %0, %1, %2" : "=v"(p3) : "v"(a1[2]), "v"(a1[3]));
      uint4v u = {p0, p1, p2, p3};
      af[mi] = __builtin_bit_cast(bf16x8, u);
    }
#pragma unroll
    for (int mi = 0; mi < 4; ++mi)
#pragma unroll
      for (int ni = 0; ni < 4; ++ni)
        acc[mi][ni] = __builtin_amdgcn_mfma_f32_16x16x32_bf16(
            af[mi], bfr[ni], acc[mi][ni], 0, 0, 0);
    asm volatile("s_waitcnt vmcnt(0)" ::: "memory");
    __builtin_amdgcn_s_barrier();
  }
#undef STAGE

  // vectorized epilogue: restage C tile (bias applied) in As (now free)
  unsigned short* Cs = reinterpret_cast<unsigned short*>(&As[0][0][0]);  // 32 KB
#pragma unroll
  for (int ni = 0; ni < 4; ++ni) {
    const float bv = bias[bn + wc + ni * 16 + row16];
#pragma unroll
    for (int mi = 0; mi < 4; ++mi)
#pragma unroll
      for (int r2 = 0; r2 < 4; ++r2)
        Cs[(wr + mi * 16 + kgrp * 4 + r2) * 128 + wc + ni * 16 + row16] =
            f2bf(acc[mi][ni][r2] + bv);
  }
  __syncthreads();
#pragma unroll
  for (int j = 0; j < 8; ++j) {
    const int row = j * 16 + (tid >> 4);
    const int col = (tid & 15) * 8;
    ushort8 v = *reinterpret_cast<const ushort8*>(&Cs[row * 128 + col]);
    *reinterpret_cast<ushort8*>(&C[(size_t)(bm + row) * N + bn + col]) = v;
  }
}

// ------- GEMM2 (r14): C[M][N] = A[M][K](bf16) * B[N][K]^T + bias -------
template <int BM, int BN, int WM, int WN, int BK, int OUT_BF16>
__global__ __launch_bounds__(256) void gemm_bt(
    const unsigned short* __restrict__ A, const unsigned short* __restrict__ B,
    const float* __restrict__ bias, void* __restrict__ Cv,
    int M, int N, int K) {
  __shared__ unsigned short As[2][BM][BK];
  __shared__ unsigned short Bs[2][BN][BK];
  const int tid = threadIdx.x;
  const int lane = tid & 63;
  const int wid = tid >> 6;

  const int nwg = gridDim.x * gridDim.y;
  const int orig = blockIdx.y * gridDim.x + blockIdx.x;
  const int q = nwg >> 3, r = nwg & 7;
  const int xcd = orig & 7, lid = orig >> 3;
  const int swz = (xcd < r ? xcd * (q + 1) : r * (q + 1) + (xcd - r) * q) + lid;
  const int bm = (swz / gridDim.x) * BM;
  const int bn = (swz % gridDim.x) * BN;

  const int NWC = BN / WN;
  const int wr = (wid / NWC) * WM;
  const int wc = (wid % NWC) * WN;
  const int row16 = lane & 15;
  const int kgrp = lane >> 4;
  const int rsw = (BK == 64) ? (row16 & 7) : (row16 & 3);

  const int RPI = 1024 / (BK * 2);
  const int lrow = (BK == 64) ? (lane >> 3) : (lane >> 2);
  const int lch = (BK == 64) ? ((lane & 7) ^ (lane >> 3))
                             : ((lane & 3) ^ ((lane >> 2) & 3));
  const int srA = wid * (BM / 4) + lrow;
  const int srB = wid * (BN / 4) + lrow;
  const unsigned short* gA = A + (size_t)(bm + srA) * K + lch * 8;
  const unsigned short* gB = B + (size_t)(bn + srB) * K + lch * 8;
  const size_t KR = (size_t)RPI * K;

#define STAGE(buf, k0)                                                     \
  {                                                                        \
    _Pragma("unroll") for (int j = 0; j < BM / (4 * RPI); ++j)             \
        gl_lds16(gA + j * KR + (k0),                                       \
                 &As[buf][wid * (BM / 4) + j * RPI][0]);                   \
    _Pragma("unroll") for (int j = 0; j < BN / (4 * RPI); ++j)             \
        gl_lds16(gB + j * KR + (k0),                                       \
                 &Bs[buf][wid * (BN / 4) + j * RPI][0]);                   \
  }

  f32x4 acc[WM / 16][WN / 16] = {};

  STAGE(0, 0);
  asm volatile("s_waitcnt vmcnt(0)" ::: "memory");
  __builtin_amdgcn_s_barrier();

  const int NT = K / BK;
  for (int t = 0; t < NT; ++t) {
    const int cur = t & 1;
    if (t + 1 < NT) STAGE(cur ^ 1, (t + 1) * BK);
    bf16x8 af[WM / 16][BK / 32], bfr[WN / 16][BK / 32];
#pragma unroll
    for (int mi = 0; mi < WM / 16; ++mi)
#pragma unroll
      for (int kh = 0; kh < BK / 32; ++kh)
        af[mi][kh] = *reinterpret_cast<const bf16x8*>(
            &As[cur][wr + mi * 16 + row16][((kh * 4 + kgrp) ^ rsw) * 8]);
#pragma unroll
    for (int ni = 0; ni < WN / 16; ++ni)
#pragma unroll
      for (int kh = 0; kh < BK / 32; ++kh)
        bfr[ni][kh] = *reinterpret_cast<const bf16x8*>(
            &Bs[cur][wc + ni * 16 + row16][((kh * 4 + kgrp) ^ rsw) * 8]);
#pragma unroll
    for (int kh = 0; kh < BK / 32; ++kh)
#pragma unroll
      for (int mi = 0; mi < WM / 16; ++mi)
#pragma unroll
        for (int ni = 0; ni < WN / 16; ++ni)
          acc[mi][ni] = __builtin_amdgcn_mfma_f32_16x16x32_bf16(
              af[mi][kh], bfr[ni][kh], acc[mi][ni], 0, 0, 0);
    asm volatile("s_waitcnt vmcnt(0)" ::: "memory");
    __builtin_amdgcn_s_barrier();
  }
#undef STAGE

  if constexpr (OUT_BF16 == 1) {
    unsigned short* Cs = &As[0][0][0];
#pragma unroll
    for (int ni = 0; ni < WN / 16; ++ni) {
      const float bv = bias[bn + wc + ni * 16 + row16];
#pragma unroll
      for (int mi = 0; mi < WM / 16; ++mi)
#pragma unroll
        for (int r2 = 0; r2 < 4; ++r2)
          Cs[(wr + mi * 16 + kgrp * 4 + r2) * 128 + wc + ni * 16 + row16] =
              f2bf(acc[mi][ni][r2] + bv);
    }
    __syncthreads();
    unsigned short* Cq = reinterpret_cast<unsigned short*>(Cv);
#pragma unroll
    for (int j = 0; j < 8; ++j) {
      const int row = j * 16 + (tid >> 4);
      const int col = (tid & 15) * 8;
      ushort8 v = *reinterpret_cast<const ushort8*>(&Cs[row * 128 + col]);
      *reinterpret_cast<ushort8*>(&Cq[(size_t)(bm + row) * N + bn + col]) = v;
    }
  } else {
#pragma unroll
    for (int ni = 0; ni < WN / 16; ++ni) {
      const int gcol = bn + wc + ni * 16 + row16;
      const float bv = bias[gcol];
#pragma unroll
      for (int mi = 0; mi < WM / 16; ++mi) {
#pragma unroll
        for (int r2 = 0; r2 < 4; ++r2) {
          const int grow = bm + wr + mi * 16 + kgrp * 4 + r2;
          reinterpret_cast<float*>(Cv)[(size_t)grow * N + gcol] =
              acc[mi][ni][r2] + bv;
        }
      }
    }
  }
}

// ---------------- local (banded) attention (r13/r14 best) ----------------
__global__ __launch_bounds__(256) void attn_local(
    const unsigned short* __restrict__ qkv, unsigned short* __restrict__ ctx,
    int S) {
  __shared__ unsigned Vt[64][76];            // 19456 B
  __shared__ unsigned short Ps[4][16][104];  // 13312 B

  const int tid = threadIdx.x;
  const int lane = tid & 63;
  const int wid = tid >> 6;

  const int nqb = S >> 6;
  const int nwg = nqb * 16;
  const int orig = blockIdx.y * gridDim.x + blockIdx.x;
  const int cpx = nwg >> 3;
  const int swzb = (orig & 7) * cpx + (orig >> 3);
  const int q0 = (swzb % nqb) * 64;
  const int bh = swzb / nqb;
  const int b = bh >> 3;
  const int h = bh & 7;

  const int row16 = lane & 15;
  const int kgrp = lane >> 4;
  const size_t bS = (size_t)b * S;

  {
    const int k2 = tid >> 2;
    const int dq = (tid & 3) * 16;
    const int ra = iclamp(q0 - 32 + 2 * k2, 0, S - 1);
    const int rb = iclamp(q0 - 32 + 2 * k2 + 1, 0, S - 1);
    const unsigned short* pa = qkv + (bS + ra) * 1536 + 1024 + h * 64 + dq;
    const unsigned short* pb = qkv + (bS + rb) * 1536 + 1024 + h * 64 + dq;
    ushort8 a0 = reinterpret_cast<const ushort8*>(pa)[0];
    ushort8 a1 = reinterpret_cast<const ushort8*>(pa)[1];
    ushort8 b0 = reinterpret_cast<const ushort8*>(pb)[0];
    ushort8 b1 = reinterpret_cast<const ushort8*>(pb)[1];
#pragma unroll
    for (int d = 0; d < 8; ++d) {
      Vt[dq + d][k2] = (unsigned)a0[d] | ((unsigned)b0[d] << 16);
      Vt[dq + 8 + d][k2] = (unsigned)a1[d] | ((unsigned)b1[d] << 16);
    }
    const int zr = tid >> 2;
    const int zc = 64 + (tid & 3) * 2;
    Vt[zr][zc] = 0u;
    Vt[zr][zc + 1] = 0u;
  }

  bf16x8 qf0, qf1;
  {
    const unsigned short* qp =
        qkv + (bS + q0 + wid * 16 + row16) * 1536 + h * 64;
    qf0 = *reinterpret_cast<const bf16x8*>(qp + kgrp * 8);
    qf1 = *reinterpret_cast<const bf16x8*>(qp + 32 + kgrp * 8);
  }

  f32x4 sc[5];
#pragma unroll
  for (int t = 0; t < 5; ++t) {
    const int key = iclamp(q0 - 32 + (wid + t) * 16 + row16, 0, S - 1);
    const unsigned short* kp = qkv + (bS + key) * 1536 + 512 + h * 64;
    bf16x8 kf0 = *reinterpret_cast<const bf16x8*>(kp + kgrp * 8);
    bf16x8 kf1 = *reinterpret_cast<const bf16x8*>(kp + 32 + kgrp * 8);
    f32x4 s = {0.f, 0.f, 0.f, 0.f};
    s = __builtin_amdgcn_mfma_f32_16x16x32_bf16(qf0, kf0, s, 0, 0, 0);
    s = __builtin_amdgcn_mfma_f32_16x16x32_bf16(qf1, kf1, s, 0, 0, 0);
    sc[t] = s;
  }

  const int ccol = row16;
  const int crow4 = kgrp * 4;
  float rm[4] = {-INFINITY, -INFINITY, -INFINITY, -INFINITY};
#pragma unroll
  for (int t = 0; t < 5; ++t)
#pragma unroll
    for (int r = 0; r < 4; ++r) {
      const int key_abs = q0 - 32 + (wid + t) * 16 + ccol;
      const int diff = -32 + t * 16 + ccol - crow4 - r;
      float s = sc[t][r] * 0.125f;
      const bool valid =
          (diff >= -32) && (diff <= 32) && (key_abs >= 0) && (key_abs < S);
      s = valid ? s : -INFINITY;
      sc[t][r] = s;
      rm[r] = fmaxf(rm[r], s);
    }
#pragma unroll
  for (int off = 1; off < 16; off <<= 1)
#pragma unroll
    for (int r = 0; r < 4; ++r) rm[r] = fmaxf(rm[r], __shfl_xor(rm[r], off, 64));
  float rs[4] = {0.f, 0.f, 0.f, 0.f};
#pragma unroll
  for (int t = 0; t < 5; ++t)
#pragma unroll
    for (int r = 0; r < 4; ++r) {
      const float p = __expf(sc[t][r] - rm[r]);
      sc[t][r] = p;
      rs[r] += p;
    }
#pragma unroll
  for (int off = 1; off < 16; off <<= 1)
#pragma unroll
    for (int r = 0; r < 4; ++r) rs[r] += __shfl_xor(rs[r], off, 64);

#pragma unroll
  for (int t = 0; t < 5; ++t)
#pragma unroll
    for (int r = 0; r < 4; ++r)
      Ps[wid][crow4 + r][t * 16 + ccol] = f2bf(sc[t][r]);
#pragma unroll
  for (int j = 0; j < 4; ++j) Ps[wid][row16][80 + kgrp * 4 + j] = 0;

  __syncthreads();

  f32x4 cacc[4] = {};
#pragma unroll
  for (int kc = 0; kc < 3; ++kc) {
    bf16x8 pf = *reinterpret_cast<const bf16x8*>(&Ps[wid][row16][kc * 32 + kgrp * 8]);
#pragma unroll
    for (int ni = 0; ni < 4; ++ni) {
      bf16x8 vf = *reinterpret_cast<const bf16x8*>(
          &Vt[ni * 16 + row16][wid * 8 + kc * 16 + kgrp * 4]);
      cacc[ni] = __builtin_amdgcn_mfma_f32_16x16x32_bf16(pf, vf, cacc[ni], 0, 0, 0);
    }
  }

  float inv[4];
#pragma unroll
  for (int r = 0; r < 4; ++r) inv[r] = 1.0f / rs[r];
#pragma unroll
  for (int ni = 0; ni < 4; ++ni)
#pragma unroll
    for (int r = 0; r < 4; ++r)
      Ps[wid][crow4 + r][ni * 16 + ccol] = f2bf(cacc[ni][r] * inv[r]);
#pragma unroll
  for (int j = 0; j < 2; ++j) {
    ushort8 vv = *reinterpret_cast<const ushort8*>(
        &Ps[wid][j * 8 + (lane >> 3)][(lane & 7) * 8]);
    *reinterpret_cast<ushort8*>(
        &ctx[(bS + q0 + wid * 16 + j * 8 + (lane >> 3)) * 512 + h * 64 +
             (lane & 7) * 8]) = vv;
  }
}

extern "C" void kernel_launch(void* const* d_in, const int* in_sizes, int n_in,
                              void* d_out, int out_size, void* d_ws, size_t ws_size,
                              hipStream_t stream) {
  const float* x = (const float*)d_in[0];
  const float* w_in = (const float*)d_in[1];
  const float* b_in = (const float*)d_in[2];
  const float* w_out = (const float*)d_in[3];
  const float* b_out = (const float*)d_in[4];
  float* out = (float*)d_out;

  const int B = 2, S = 4096, D = 512;
  const int BS = B * S;  // 8192

  char* ws = (char*)d_ws;
  unsigned short* wbin = (unsigned short*)(ws + 8388608);  //  1,572,864
  unsigned short* wbo = (unsigned short*)(ws + 9961472);   //    524,288
  unsigned short* qkvb = (unsigned short*)(ws + 10485760); // 25,165,824
  unsigned short* ctxb = (unsigned short*)(ws + 35651584); //  8,388,608

  // weights fp32->bf16 only (x is consumed fp32 by gemm_xf32_bt)
  cvt_w<<<256, 256, 0, stream>>>(w_in, w_out, wbin, wbo);

  // QKV projection reading x directly as fp32: [8192,512] x [1536,512]^T -> bf16
  gemm_xf32_bt<<<dim3(12, 64), 256, 0, stream>>>(x, wbin, b_in, qkvb, BS, 3 * D, D);

  // local attention -> ctx bf16 [8192,512]
  attn_local<<<dim3(S / 64, 16), 256, 0, stream>>>(qkvb, ctxb, S);

  // out projection: [8192,512] x [512,512]^T -> fp32 d_out (r14 config)
  gemm_bt<64, 128, 32, 64, 64, 0>
      <<<dim3(4, 128), 256, 0, stream>>>(ctxb, wbo, b_out, out, BS, D, D);
}

// Round 18
// 54.543 us; speedup vs baseline: 1.0344x; 1.0344x over previous
//
#include <hip/hip_runtime.h>

typedef __attribute__((ext_vector_type(8))) short bf16x8;
typedef __attribute__((ext_vector_type(8))) unsigned short ushort8;
typedef __attribute__((ext_vector_type(4))) float f32x4;

static __device__ __forceinline__ unsigned short f2bf(float f) {
  union { float f; unsigned u; } v; v.f = f;
  unsigned r = v.u + 0x7FFFu + ((v.u >> 16) & 1u);
  return (unsigned short)(r >> 16);
}
static __device__ __forceinline__ int iclamp(int x, int lo, int hi) {
  return x < lo ? lo : (x > hi ? hi : x);
}
// async global->LDS, 16B per lane; LDS dest = wave-uniform base + lane*16
static __device__ __forceinline__ void gl_lds16(const unsigned short* g,
                                                unsigned short* l) {
  __builtin_amdgcn_global_load_lds(
      (const __attribute__((address_space(1))) void*)g,
      (__attribute__((address_space(3))) void*)l, 16, 0, 0);
}

// ---------------- fused fp32 -> bf16 converts (one launch) ----------------
__global__ void cvt_all(const float* __restrict__ x,
                        const float* __restrict__ w_in,
                        const float* __restrict__ w_out,
                        unsigned short* __restrict__ xb,
                        unsigned short* __restrict__ wbin,
                        unsigned short* __restrict__ wbo) {
  const int NX4 = 1048576, NWI4 = 196608, NWO4 = 65536;  // float4 counts
  const int total = NX4 + NWI4 + NWO4;
  for (int i = blockIdx.x * blockDim.x + threadIdx.x; i < total;
       i += gridDim.x * blockDim.x) {
    const float* src;
    unsigned short* dst;
    int o;
    if (i < NX4) {
      src = x; dst = xb; o = i;
    } else if (i < NX4 + NWI4) {
      src = w_in; dst = wbin; o = i - NX4;
    } else {
      src = w_out; dst = wbo; o = i - NX4 - NWI4;
    }
    float4 v = reinterpret_cast<const float4*>(src)[o];
    ushort4 u;
    u.x = f2bf(v.x); u.y = f2bf(v.y); u.z = f2bf(v.z); u.w = f2bf(v.w);
    reinterpret_cast<ushort4*>(dst)[o] = u;
  }
}

// ------- GEMM: C[M][N] = A[M][K](bf16) * B[N][K](bf16)^T + bias -------
// (r14: 2-phase dbuf, gl_lds w16 pre-swizzled source, post-MFMA drain,
//  BK template; OUT_BF16: vectorized epilogue via C-restage)
template <int BM, int BN, int WM, int WN, int BK, int OUT_BF16>
__global__ __launch_bounds__(256) void gemm_bt(
    const unsigned short* __restrict__ A, const unsigned short* __restrict__ B,
    const float* __restrict__ bias, void* __restrict__ Cv,
    int M, int N, int K) {
  __shared__ unsigned short As[2][BM][BK];
  __shared__ unsigned short Bs[2][BN][BK];
  const int tid = threadIdx.x;
  const int lane = tid & 63;
  const int wid = tid >> 6;

  const int nwg = gridDim.x * gridDim.y;
  const int orig = blockIdx.y * gridDim.x + blockIdx.x;
  const int q = nwg >> 3, r = nwg & 7;
  const int xcd = orig & 7, lid = orig >> 3;
  const int swz = (xcd < r ? xcd * (q + 1) : r * (q + 1) + (xcd - r) * q) + lid;
  const int bm = (swz / gridDim.x) * BM;
  const int bn = (swz % gridDim.x) * BN;

  const int NWC = BN / WN;
  const int wr = (wid / NWC) * WM;
  const int wc = (wid % NWC) * WN;
  const int row16 = lane & 15;
  const int kgrp = lane >> 4;
  const int rsw = (BK == 64) ? (row16 & 7) : (row16 & 3);

  const int RPI = 1024 / (BK * 2);  // rows per gl_lds instr: 8 or 16
  const int lrow = (BK == 64) ? (lane >> 3) : (lane >> 2);
  const int lch = (BK == 64) ? ((lane & 7) ^ (lane >> 3))
                             : ((lane & 3) ^ ((lane >> 2) & 3));
  const int srA = wid * (BM / 4) + lrow;
  const int srB = wid * (BN / 4) + lrow;
  const unsigned short* gA = A + (size_t)(bm + srA) * K + lch * 8;
  const unsigned short* gB = B + (size_t)(bn + srB) * K + lch * 8;
  const size_t KR = (size_t)RPI * K;

#define STAGE(buf, k0)                                                     \
  {                                                                        \
    _Pragma("unroll") for (int j = 0; j < BM / (4 * RPI); ++j)             \
        gl_lds16(gA + j * KR + (k0),                                       \
                 &As[buf][wid * (BM / 4) + j * RPI][0]);                   \
    _Pragma("unroll") for (int j = 0; j < BN / (4 * RPI); ++j)             \
        gl_lds16(gB + j * KR + (k0),                                       \
                 &Bs[buf][wid * (BN / 4) + j * RPI][0]);                   \
  }

  f32x4 acc[WM / 16][WN / 16] = {};

  STAGE(0, 0);
  asm volatile("s_waitcnt vmcnt(0)" ::: "memory");
  __builtin_amdgcn_s_barrier();

  const int NT = K / BK;
  for (int t = 0; t < NT; ++t) {
    const int cur = t & 1;
    if (t + 1 < NT) STAGE(cur ^ 1, (t + 1) * BK);
    bf16x8 af[WM / 16][BK / 32], bfr[WN / 16][BK / 32];
#pragma unroll
    for (int mi = 0; mi < WM / 16; ++mi)
#pragma unroll
      for (int kh = 0; kh < BK / 32; ++kh)
        af[mi][kh] = *reinterpret_cast<const bf16x8*>(
            &As[cur][wr + mi * 16 + row16][((kh * 4 + kgrp) ^ rsw) * 8]);
#pragma unroll
    for (int ni = 0; ni < WN / 16; ++ni)
#pragma unroll
      for (int kh = 0; kh < BK / 32; ++kh)
        bfr[ni][kh] = *reinterpret_cast<const bf16x8*>(
            &Bs[cur][wc + ni * 16 + row16][((kh * 4 + kgrp) ^ rsw) * 8]);
#pragma unroll
    for (int kh = 0; kh < BK / 32; ++kh)
#pragma unroll
      for (int mi = 0; mi < WM / 16; ++mi)
#pragma unroll
        for (int ni = 0; ni < WN / 16; ++ni)
          acc[mi][ni] = __builtin_amdgcn_mfma_f32_16x16x32_bf16(
              af[mi][kh], bfr[ni][kh], acc[mi][ni], 0, 0, 0);
    asm volatile("s_waitcnt vmcnt(0)" ::: "memory");
    __builtin_amdgcn_s_barrier();
  }
#undef STAGE

  if constexpr (OUT_BF16 == 1) {
    unsigned short* Cs = &As[0][0][0];  // >= 128*128 ushorts (free now)
#pragma unroll
    for (int ni = 0; ni < WN / 16; ++ni) {
      const float bv = bias[bn + wc + ni * 16 + row16];
#pragma unroll
      for (int mi = 0; mi < WM / 16; ++mi)
#pragma unroll
        for (int r2 = 0; r2 < 4; ++r2)
          Cs[(wr + mi * 16 + kgrp * 4 + r2) * 128 + wc + ni * 16 + row16] =
              f2bf(acc[mi][ni][r2] + bv);
    }
    __syncthreads();
    unsigned short* Cq = reinterpret_cast<unsigned short*>(Cv);
#pragma unroll
    for (int j = 0; j < 8; ++j) {
      const int row = j * 16 + (tid >> 4);
      const int col = (tid & 15) * 8;
      ushort8 v = *reinterpret_cast<const ushort8*>(&Cs[row * 128 + col]);
      *reinterpret_cast<ushort8*>(&Cq[(size_t)(bm + row) * N + bn + col]) = v;
    }
  } else {
#pragma unroll
    for (int ni = 0; ni < WN / 16; ++ni) {
      const int gcol = bn + wc + ni * 16 + row16;
      const float bv = bias[gcol];
#pragma unroll
      for (int mi = 0; mi < WM / 16; ++mi) {
#pragma unroll
        for (int r2 = 0; r2 < 4; ++r2) {
          const int grow = bm + wr + mi * 16 + kgrp * 4 + r2;
          reinterpret_cast<float*>(Cv)[(size_t)grow * N + gcol] =
              acc[mi][ni][r2] + bv;
        }
      }
    }
  }
}

// ---------------- local (banded) attention, v3 + XCD-chunked grid + T5 ----------------
// (r13/r14 best structure; s_setprio(1) wrapped around MFMA clusters only)
__global__ __launch_bounds__(256) void attn_local(
    const unsigned short* __restrict__ qkv, unsigned short* __restrict__ ctx,
    int S) {
  __shared__ unsigned Vt[64][76];            // 19456 B
  __shared__ unsigned short Ps[4][16][104];  // 13312 B

  const int tid = threadIdx.x;
  const int lane = tid & 63;
  const int wid = tid >> 6;

  const int nqb = S >> 6;
  const int nwg = nqb * 16;
  const int orig = blockIdx.y * gridDim.x + blockIdx.x;
  const int cpx = nwg >> 3;
  const int swzb = (orig & 7) * cpx + (orig >> 3);
  const int q0 = (swzb % nqb) * 64;
  const int bh = swzb / nqb;
  const int b = bh >> 3;
  const int h = bh & 7;

  const int row16 = lane & 15;
  const int kgrp = lane >> 4;
  const size_t bS = (size_t)b * S;

  // ---- stage V transposed (packed key pairs) ----
  {
    const int k2 = tid >> 2;
    const int dq = (tid & 3) * 16;
    const int ra = iclamp(q0 - 32 + 2 * k2, 0, S - 1);
    const int rb = iclamp(q0 - 32 + 2 * k2 + 1, 0, S - 1);
    const unsigned short* pa = qkv + (bS + ra) * 1536 + 1024 + h * 64 + dq;
    const unsigned short* pb = qkv + (bS + rb) * 1536 + 1024 + h * 64 + dq;
    ushort8 a0 = reinterpret_cast<const ushort8*>(pa)[0];
    ushort8 a1 = reinterpret_cast<const ushort8*>(pa)[1];
    ushort8 b0 = reinterpret_cast<const ushort8*>(pb)[0];
    ushort8 b1 = reinterpret_cast<const ushort8*>(pb)[1];
#pragma unroll
    for (int d = 0; d < 8; ++d) {
      Vt[dq + d][k2] = (unsigned)a0[d] | ((unsigned)b0[d] << 16);
      Vt[dq + 8 + d][k2] = (unsigned)a1[d] | ((unsigned)b1[d] << 16);
    }
    const int zr = tid >> 2;
    const int zc = 64 + (tid & 3) * 2;
    Vt[zr][zc] = 0u;
    Vt[zr][zc + 1] = 0u;
  }

  // ---- Q fragments (direct from global) ----
  bf16x8 qf0, qf1;
  {
    const unsigned short* qp =
        qkv + (bS + q0 + wid * 16 + row16) * 1536 + h * 64;
    qf0 = *reinterpret_cast<const bf16x8*>(qp + kgrp * 8);
    qf1 = *reinterpret_cast<const bf16x8*>(qp + 32 + kgrp * 8);
  }

  // ---- QK^T: 5 key tiles, K direct from global (clamped rows) ----
  f32x4 sc[5];
#pragma unroll
  for (int t = 0; t < 5; ++t) {
    const int key = iclamp(q0 - 32 + (wid + t) * 16 + row16, 0, S - 1);
    const unsigned short* kp = qkv + (bS + key) * 1536 + 512 + h * 64;
    bf16x8 kf0 = *reinterpret_cast<const bf16x8*>(kp + kgrp * 8);
    bf16x8 kf1 = *reinterpret_cast<const bf16x8*>(kp + 32 + kgrp * 8);
    f32x4 s = {0.f, 0.f, 0.f, 0.f};
    __builtin_amdgcn_s_setprio(1);  // T5: favor MFMA wave on CU scheduler
    s = __builtin_amdgcn_mfma_f32_16x16x32_bf16(qf0, kf0, s, 0, 0, 0);
    s = __builtin_amdgcn_mfma_f32_16x16x32_bf16(qf1, kf1, s, 0, 0, 0);
    __builtin_amdgcn_s_setprio(0);
    sc[t] = s;
  }

  // ---- mask + softmax ----
  const int ccol = row16;
  const int crow4 = kgrp * 4;
  float rm[4] = {-INFINITY, -INFINITY, -INFINITY, -INFINITY};
#pragma unroll
  for (int t = 0; t < 5; ++t)
#pragma unroll
    for (int r = 0; r < 4; ++r) {
      const int key_abs = q0 - 32 + (wid + t) * 16 + ccol;
      const int diff = -32 + t * 16 + ccol - crow4 - r;
      float s = sc[t][r] * 0.125f;
      const bool valid =
          (diff >= -32) && (diff <= 32) && (key_abs >= 0) && (key_abs < S);
      s = valid ? s : -INFINITY;
      sc[t][r] = s;
      rm[r] = fmaxf(rm[r], s);
    }
#pragma unroll
  for (int off = 1; off < 16; off <<= 1)
#pragma unroll
    for (int r = 0; r < 4; ++r) rm[r] = fmaxf(rm[r], __shfl_xor(rm[r], off, 64));
  float rs[4] = {0.f, 0.f, 0.f, 0.f};
#pragma unroll
  for (int t = 0; t < 5; ++t)
#pragma unroll
    for (int r = 0; r < 4; ++r) {
      const float p = __expf(sc[t][r] - rm[r]);
      sc[t][r] = p;
      rs[r] += p;
    }
#pragma unroll
  for (int off = 1; off < 16; off <<= 1)
#pragma unroll
    for (int r = 0; r < 4; ++r) rs[r] += __shfl_xor(rs[r], off, 64);

  // ---- P -> LDS (bf16), zero-pad keys 80..95 ----
#pragma unroll
  for (int t = 0; t < 5; ++t)
#pragma unroll
    for (int r = 0; r < 4; ++r)
      Ps[wid][crow4 + r][t * 16 + ccol] = f2bf(sc[t][r]);
#pragma unroll
  for (int j = 0; j < 4; ++j) Ps[wid][row16][80 + kgrp * 4 + j] = 0;

  __syncthreads();

  // ---- PV: ctx[16x64] = P[16x96] * V[96x64] ----
  f32x4 cacc[4] = {};
#pragma unroll
  for (int kc = 0; kc < 3; ++kc) {
    bf16x8 pf = *reinterpret_cast<const bf16x8*>(&Ps[wid][row16][kc * 32 + kgrp * 8]);
    bf16x8 vf[4];
#pragma unroll
    for (int ni = 0; ni < 4; ++ni)
      vf[ni] = *reinterpret_cast<const bf16x8*>(
          &Vt[ni * 16 + row16][wid * 8 + kc * 16 + kgrp * 4]);
    __builtin_amdgcn_s_setprio(1);  // T5
#pragma unroll
    for (int ni = 0; ni < 4; ++ni)
      cacc[ni] = __builtin_amdgcn_mfma_f32_16x16x32_bf16(pf, vf[ni], cacc[ni], 0, 0, 0);
    __builtin_amdgcn_s_setprio(0);
  }

  // ---- normalize; restage tile in wave-private Ps; coalesced store ----
  float inv[4];
#pragma unroll
  for (int r = 0; r < 4; ++r) inv[r] = 1.0f / rs[r];
#pragma unroll
  for (int ni = 0; ni < 4; ++ni)
#pragma unroll
    for (int r = 0; r < 4; ++r)
      Ps[wid][crow4 + r][ni * 16 + ccol] = f2bf(cacc[ni][r] * inv[r]);
  // wave-private buffer: write->read ordered by lgkmcnt (no barrier needed)
#pragma unroll
  for (int j = 0; j < 2; ++j) {
    ushort8 vv = *reinterpret_cast<const ushort8*>(
        &Ps[wid][j * 8 + (lane >> 3)][(lane & 7) * 8]);
    *reinterpret_cast<ushort8*>(
        &ctx[(bS + q0 + wid * 16 + j * 8 + (lane >> 3)) * 512 + h * 64 +
             (lane & 7) * 8]) = vv;
  }
}

extern "C" void kernel_launch(void* const* d_in, const int* in_sizes, int n_in,
                              void* d_out, int out_size, void* d_ws, size_t ws_size,
                              hipStream_t stream) {
  const float* x = (const float*)d_in[0];
  const float* w_in = (const float*)d_in[1];
  const float* b_in = (const float*)d_in[2];
  const float* w_out = (const float*)d_in[3];
  const float* b_out = (const float*)d_in[4];
  float* out = (float*)d_out;

  const int B = 2, S = 4096, D = 512;
  const int BS = B * S;  // 8192

  char* ws = (char*)d_ws;
  unsigned short* xb = (unsigned short*)(ws + 0);          //  8,388,608
  unsigned short* wbin = (unsigned short*)(ws + 8388608);  //  1,572,864
  unsigned short* wbo = (unsigned short*)(ws + 9961472);   //    524,288
  unsigned short* qkvb = (unsigned short*)(ws + 10485760); // 25,165,824
  unsigned short* ctxb = (unsigned short*)(ws + 35651584); //  8,388,608

  // all fp32->bf16 converts in one launch
  cvt_all<<<2048, 256, 0, stream>>>(x, w_in, w_out, xb, wbin, wbo);

  // QKV projection: [8192,512] x [1536,512]^T -> bf16 [8192,1536]
  gemm_bt<128, 128, 64, 64, 32, 1>
      <<<dim3(12, 64), 256, 0, stream>>>(xb, wbin, b_in, qkvb, BS, 3 * D, D);

  // local attention -> ctx bf16 [8192,512]; 64 q/block (r13 best config)
  attn_local<<<dim3(S / 64, 16), 256, 0, stream>>>(qkvb, ctxb, S);

  // out projection: [8192,512] x [512,512]^T -> fp32 d_out (r14 config)
  gemm_bt<64, 128, 32, 64, 64, 0>
      <<<dim3(4, 128), 256, 0, stream>>>(ctxb, wbo, b_out, out, BS, D, D);
}